// Round 5
// baseline (24655.684 us; speedup 1.0000x reference)
//
#include <hip/hip_runtime.h>

// ---------------------------------------------------------------------------
// Persistent seq2seq LSTM, v5: 2D (N x K) decomposition, zero fences.
// 256 blocks x 1024 threads (16 waves: mt=w&7 M-tile, nh=w>>3 N-half).
// Block p: n=p>>3 (unit group: units n*32..n*32+31), k=p&7 slab role:
//   k<4 : x-slab (K=[k*128,k*128+128) of x/y) ; decoder: softmax row n*4+k
//   k>=4: h-slab (K=512+[(k-4)*256, ...+256))  ; decoder: fc f=n*4+(k-4)
// Per step: slab GEMM (split-bf16, 3 MFMA terms) -> WT 64KB fp32 partial C
// -> pline[n] count -> every block reduces its 16 gate-cols (4 units x 4
// gates, same unit map as v4: col = q*1024 + p*4 + u) + LSTM pointwise
// (c in regs) -> pack h split-bf16 -> hln. Decoder adds fc (h-blocks) and
// softmax+y-pack (x-blocks) chained by fln/yln counts.
// NO acquire fences: all cross-block payloads are WT-stored (agent atomics)
// and read via agent-scope bypass loads (LLC-direct, proven in v2-v4 for
// counters/fp). x is read from the immutable input w/ in-register split.
// ---------------------------------------------------------------------------

#define TS 384
#define DBASE (TS + 2)

typedef __attribute__((ext_vector_type(8))) short bf16x8;
typedef __attribute__((ext_vector_type(4))) float f32x4;

#define WS_C   8192u
#define WS_HP  16785408u                 // 8192 + 256*65536
#define WS_YP  17833984u                 // + 2*524288
#define WS_FPD 18096128u                 // + 262144
#define WS_TOTAL 20193280u               // + 2097152

__device__ __forceinline__ unsigned short bf16r(float v) {
  unsigned u = __float_as_uint(v);
  u += 0x7FFFu + ((u >> 16) & 1u);
  return (unsigned short)(u >> 16);
}
__device__ __forceinline__ float bf2f(unsigned short h) {
  return __uint_as_float(((unsigned)h) << 16);
}
__device__ __forceinline__ void split2(float v, short& hi, short& lo) {
  unsigned short h = bf16r(v);
  float r = v - bf2f(h);
  hi = (short)h; lo = (short)bf16r(r);
}
__device__ __forceinline__ float sigm(float v)  { return 1.0f / (1.0f + __expf(-v)); }
__device__ __forceinline__ float tanhfa(float v){ return 1.0f - 2.0f / (__expf(2.0f*v) + 1.0f); }

__device__ __forceinline__ void st_u64(void* p, unsigned long long v) {
  __hip_atomic_store((unsigned long long*)p, v, __ATOMIC_RELAXED, __HIP_MEMORY_SCOPE_AGENT);
}
__device__ __forceinline__ void st_f32(float* p, float v) {
  __hip_atomic_store(p, v, __ATOMIC_RELAXED, __HIP_MEMORY_SCOPE_AGENT);
}
__device__ __forceinline__ float ld_f32(const float* p) {
  return __hip_atomic_load(p, __ATOMIC_RELAXED, __HIP_MEMORY_SCOPE_AGENT);
}
__device__ __forceinline__ unsigned ldc(const unsigned* p) {
  return __hip_atomic_load(p, __ATOMIC_RELAXED, __HIP_MEMORY_SCOPE_AGENT);
}
union FRAG { unsigned long long q[2]; bf16x8 v; };
__device__ __forceinline__ bf16x8 ld_frag(const short* base) {
  FRAG u;
  u.q[0] = __hip_atomic_load((const unsigned long long*)base, __ATOMIC_RELAXED, __HIP_MEMORY_SCOPE_AGENT);
  u.q[1] = __hip_atomic_load((const unsigned long long*)(base + 4), __ATOMIC_RELAXED, __HIP_MEMORY_SCOPE_AGENT);
  return u.v;
}

// ---- sync -------------------------------------------------------------------
__device__ __forceinline__ void arrive(unsigned* line) {
  asm volatile("s_waitcnt vmcnt(0)" ::: "memory");
  __syncthreads();
  if (threadIdx.x == 0)
    __hip_atomic_fetch_add(line, 1u, __ATOMIC_RELAXED, __HIP_MEMORY_SCOPE_AGENT);
}
__device__ __forceinline__ void wait4(const unsigned* base, unsigned target, int* sDead) {
  if (threadIdx.x == 0) {
    unsigned spins = 0;
    for (;;) {
      unsigned c0 = ldc(base), c1 = ldc(base + 64);
      unsigned c2 = ldc(base + 128), c3 = ldc(base + 192);
      if (c0 >= target && c1 >= target && c2 >= target && c3 >= target) break;
      __builtin_amdgcn_s_sleep(1);
      if (++spins > (1u << 19)) { *sDead = 1; break; }
    }
  }
  __syncthreads();
}
__device__ __forceinline__ void wait1(const unsigned* line, unsigned target, int* sDead) {
  if (threadIdx.x == 0) {
    unsigned spins = 0;
    while (ldc(line) < target) {
      __builtin_amdgcn_s_sleep(1);
      if (++spins > (1u << 19)) { *sDead = 1; break; }
    }
  }
  __syncthreads();
}

// ---- weight loaders --------------------------------------------------------
__device__ void load_gw(const float* __restrict__ Wx, const float* __restrict__ Wh,
                        int n, int k, short* sBh, short* sBl) {
  if (k < 4) {
    for (int idx = threadIdx.x; idx < 16384; idx += 1024) {
      int j = idx & 7, l = (idx >> 3) & 63, kb = (idx >> 9) & 3, nt = idx >> 11;
      int K = k * 128 + kb * 32 + ((l >> 4) << 3) + j;
      int c = nt * 16 + (l & 15);
      int gcol = ((c >> 2) & 3) * 1024 + n * 32 + ((c >> 4) << 2) + (c & 3);
      short hi, lo; split2(Wx[(size_t)K * 4096 + gcol], hi, lo);
      sBh[idx] = hi; sBl[idx] = lo;
    }
  } else {
    for (int idx = threadIdx.x; idx < 32768; idx += 1024) {
      int j = idx & 7, l = (idx >> 3) & 63, kb = (idx >> 9) & 7, nt = idx >> 12;
      int K = (k - 4) * 256 + kb * 32 + ((l >> 4) << 3) + j;   // h index
      int c = nt * 16 + (l & 15);
      int gcol = ((c >> 2) & 3) * 1024 + n * 32 + ((c >> 4) << 2) + (c & 3);
      short hi, lo; split2(Wh[(size_t)K * 4096 + gcol], hi, lo);
      sBh[idx] = hi; sBl[idx] = lo;
    }
  }
}
__device__ void load_fcw(const float* __restrict__ fcW, int kg, int cg,
                         short* sFh, short* sFl) {
  for (int idx = threadIdx.x; idx < 4096; idx += 1024) {
    int j = idx & 7, l = (idx >> 3) & 63, kb = idx >> 9;
    int unit = kg * 256 + kb * 32 + ((l >> 4) << 3) + j;
    int col = cg * 16 + (l & 15);
    short hi, lo; split2(fcW[(size_t)unit * 512 + col], hi, lo);
    sFh[idx] = hi; sFl[idx] = lo;
  }
}

#define MFMA __builtin_amdgcn_mfma_f32_16x16x32_bf16

// ---- h-slab GEMM: 8 kb from h-plane (bypass), 1-deep A prefetch ------------
__device__ __forceinline__ void gemm_h(const short* hpHc, const short* hpLc,
    const short* sBh, const short* sBl, int hs, int mt, int nh, int l, f32x4* acc)
{
  const bf16x8* BH = (const bf16x8*)sBh;
  const bf16x8* BL = (const bf16x8*)sBl;
  const int kb0 = hs * 8;
  bf16x8 ah = ld_frag(hpHc + ((kb0 * 8 + mt) * 64 + l) * 8);
  bf16x8 al = ld_frag(hpLc + ((kb0 * 8 + mt) * 64 + l) * 8);
  #pragma unroll
  for (int kb = 0; kb < 8; ++kb) {
    bf16x8 ahn = ah, aln = al;
    if (kb < 7) {
      ahn = ld_frag(hpHc + (((kb0 + kb + 1) * 8 + mt) * 64 + l) * 8);
      aln = ld_frag(hpLc + (((kb0 + kb + 1) * 8 + mt) * 64 + l) * 8);
    }
    bf16x8 bh[4], bl[4];
    #pragma unroll
    for (int i = 0; i < 4; ++i) {
      bh[i] = BH[((nh * 4 + i) * 8 + kb) * 64 + l];
      bl[i] = BL[((nh * 4 + i) * 8 + kb) * 64 + l];
    }
    #pragma unroll
    for (int i = 0; i < 4; ++i) acc[i] = MFMA(ah, bh[i], acc[i], 0, 0, 0);
    #pragma unroll
    for (int i = 0; i < 4; ++i) acc[i] = MFMA(ah, bl[i], acc[i], 0, 0, 0);
    #pragma unroll
    for (int i = 0; i < 4; ++i) acc[i] = MFMA(al, bh[i], acc[i], 0, 0, 0);
    ah = ahn; al = aln;
  }
}

// ---- x-slab GEMM, encoder: direct fp32 x loads + in-register split ---------
__device__ __forceinline__ void gemm_x_enc(const float* __restrict__ xsrc,
    const short* sBh, const short* sBl, int xs, int mt, int nh, int l, f32x4* acc)
{
  const bf16x8* BH = (const bf16x8*)sBh;
  const bf16x8* BL = (const bf16x8*)sBl;
  const int row = mt * 16 + (l & 15);
  #pragma unroll
  for (int kb = 0; kb < 4; ++kb) {
    const int kc = (xs * 4 + kb) * 32 + ((l >> 4) << 3);
    const float* xp = xsrc + (size_t)row * 512 + kc;
    float4 f0 = *(const float4*)xp;
    float4 f1 = *(const float4*)(xp + 4);
    union { bf16x8 v; short s[8]; } Ah, Al;
    split2(f0.x, Ah.s[0], Al.s[0]); split2(f0.y, Ah.s[1], Al.s[1]);
    split2(f0.z, Ah.s[2], Al.s[2]); split2(f0.w, Ah.s[3], Al.s[3]);
    split2(f1.x, Ah.s[4], Al.s[4]); split2(f1.y, Ah.s[5], Al.s[5]);
    split2(f1.z, Ah.s[6], Al.s[6]); split2(f1.w, Ah.s[7], Al.s[7]);
    bf16x8 bh[4], bl[4];
    #pragma unroll
    for (int i = 0; i < 4; ++i) {
      bh[i] = BH[((nh * 4 + i) * 4 + kb) * 64 + l];
      bl[i] = BL[((nh * 4 + i) * 4 + kb) * 64 + l];
    }
    #pragma unroll
    for (int i = 0; i < 4; ++i) acc[i] = MFMA(Ah.v, bh[i], acc[i], 0, 0, 0);
    #pragma unroll
    for (int i = 0; i < 4; ++i) acc[i] = MFMA(Ah.v, bl[i], acc[i], 0, 0, 0);
    #pragma unroll
    for (int i = 0; i < 4; ++i) acc[i] = MFMA(Al.v, bh[i], acc[i], 0, 0, 0);
  }
}

// ---- x-slab GEMM, decoder: y-plane (bypass) --------------------------------
__device__ __forceinline__ void gemm_x_dec(const short* ypH, const short* ypL,
    const short* sBh, const short* sBl, int xs, int mt, int nh, int l, f32x4* acc)
{
  const bf16x8* BH = (const bf16x8*)sBh;
  const bf16x8* BL = (const bf16x8*)sBl;
  const int kb0 = xs * 4;
  bf16x8 ah = ld_frag(ypH + ((kb0 * 8 + mt) * 64 + l) * 8);
  bf16x8 al = ld_frag(ypL + ((kb0 * 8 + mt) * 64 + l) * 8);
  #pragma unroll
  for (int kb = 0; kb < 4; ++kb) {
    bf16x8 ahn = ah, aln = al;
    if (kb < 3) {
      ahn = ld_frag(ypH + (((kb0 + kb + 1) * 8 + mt) * 64 + l) * 8);
      aln = ld_frag(ypL + (((kb0 + kb + 1) * 8 + mt) * 64 + l) * 8);
    }
    bf16x8 bh[4], bl[4];
    #pragma unroll
    for (int i = 0; i < 4; ++i) {
      bh[i] = BH[((nh * 4 + i) * 4 + kb) * 64 + l];
      bl[i] = BL[((nh * 4 + i) * 4 + kb) * 64 + l];
    }
    #pragma unroll
    for (int i = 0; i < 4; ++i) acc[i] = MFMA(ah, bh[i], acc[i], 0, 0, 0);
    #pragma unroll
    for (int i = 0; i < 4; ++i) acc[i] = MFMA(ah, bl[i], acc[i], 0, 0, 0);
    #pragma unroll
    for (int i = 0; i < 4; ++i) acc[i] = MFMA(al, bh[i], acc[i], 0, 0, 0);
    ah = ahn; al = aln;
  }
}

__device__ __forceinline__ void store_C(char* ws, int p, int mt, int nh, int l,
                                        const f32x4* acc) {
  float* Cm = (float*)(ws + WS_C) + (size_t)p * 16384;
  const int r0 = mt * 16 + ((l >> 4) << 2);
  #pragma unroll
  for (int i = 0; i < 4; ++i) {
    int col = (nh * 4 + i) * 16 + (l & 15);
    float* dst = Cm + col * 128 + r0;
    union { float f[2]; unsigned long long q; } a, b;
    a.f[0] = acc[i][0]; a.f[1] = acc[i][1];
    b.f[0] = acc[i][2]; b.f[1] = acc[i][3];
    st_u64(dst, a.q); st_u64(dst + 2, b.q);
  }
}

__global__ void __launch_bounds__(1024, 1)
lstm5(const float* __restrict__ x, const float* __restrict__ h0p,
      const float* __restrict__ c0p, const float* __restrict__ eWx,
      const float* __restrict__ eWh, const float* __restrict__ eb,
      const float* __restrict__ dWx, const float* __restrict__ dWh,
      const float* __restrict__ db, const float* __restrict__ fcW,
      const float* __restrict__ fcb, float* __restrict__ out,
      char* __restrict__ ws)
{
  __shared__ __align__(16) short sBh[32768], sBl[32768];   // 128 KB
  __shared__ __align__(16) short sFh[4096], sFl[4096];     // 16 KB
  __shared__ unsigned hsplit[512];
  __shared__ float ybuf[512];
  __shared__ float red[16];
  __shared__ int sDead;

  const int p = blockIdx.x, t = threadIdx.x;
  const int w = t >> 6, l = t & 63;
  const int mt = w & 7, nh = w >> 3;
  const int n = p >> 3, k = p & 7;
  if (t == 0) sDead = 0;

  unsigned* hln  = (unsigned*)ws;
  unsigned* pln  = (unsigned*)(ws + 1024) + n * 32;
  unsigned* flnB = (unsigned*)(ws + 5376);
  unsigned* ylnB = (unsigned*)(ws + 6400);
  unsigned* my_hline = hln + (p >> 6) * 64;

  short* hpH[2]; short* hpL[2];
  #pragma unroll
  for (int b2 = 0; b2 < 2; ++b2) {
    hpH[b2] = (short*)(ws + WS_HP + b2 * 524288u);
    hpL[b2] = (short*)(ws + WS_HP + b2 * 524288u + 262144u);
  }
  short* ypH = (short*)(ws + WS_YP);
  short* ypL = (short*)(ws + WS_YP + 131072u);
  float* fp  = (float*)(ws + WS_FPD);
  const float* Cgrp = (const float*)(ws + WS_C) + (size_t)(n * 8) * 16384;

  const int row_pw = t & 127, u_pw = (t >> 7) & 3;

  // ================= init =================
  load_gw(eWx, eWh, n, k, sBh, sBl);
  if (t < 64) {                                  // h0 -> h-plane[0]
    int hg = p * 64 + t;
    int ll = hg & 63, mtt = (hg >> 6) & 7, hk = hg >> 9;
    int row = mtt * 16 + (ll & 15), kcol = hk * 32 + ((ll >> 4) << 3);
    const float* hs = h0p + (size_t)row * 1024 + kcol;
    unsigned long long h64[2] = {0, 0}, l64[2] = {0, 0};
    #pragma unroll
    for (int j = 0; j < 8; ++j) {
      short hi, lo; split2(hs[j], hi, lo);
      h64[j >> 2] |= (unsigned long long)(unsigned short)hi << ((j & 3) * 16);
      l64[j >> 2] |= (unsigned long long)(unsigned short)lo << ((j & 3) * 16);
    }
    st_u64(hpH[0] + hg * 8, h64[0]); st_u64(hpH[0] + hg * 8 + 4, h64[1]);
    st_u64(hpL[0] + hg * 8, l64[0]); st_u64(hpL[0] + hg * 8 + 4, l64[1]);
  }
  float creg = 0.f, bq0 = 0.f, bq1 = 0.f, bq2 = 0.f, bq3 = 0.f;
  if (t < 512) {
    creg = c0p[(size_t)row_pw * 1024 + p * 4 + u_pw];
    bq0 = eb[0 * 1024 + p * 4 + u_pw];
    bq1 = eb[1 * 1024 + p * 4 + u_pw];
    bq2 = eb[2 * 1024 + p * 4 + u_pw];
    bq3 = eb[3 * 1024 + p * 4 + u_pw];
  }
  arrive(my_hline);                              // -> 64*1  ("h(0) ready")

  // ================= encoder =================
  for (int st = 0; st < TS; ++st) {
    const int rp = st & 1, wp = rp ^ 1;
    f32x4 z = {0.f, 0.f, 0.f, 0.f};
    f32x4 acc[4] = {z, z, z, z};
    if (k < 4) {
      gemm_x_enc(x + (size_t)st * 65536, sBh, sBl, k, mt, nh, l, acc);
      wait4(hln, 64u * (st + 1), &sDead);        // C-WAR gate (reduce st-1 done)
      if (sDead) return;
    } else {
      wait4(hln, 64u * (st + 1), &sDead);        // h(st) ready
      if (sDead) return;
      gemm_h(hpH[rp], hpL[rp], sBh, sBl, k - 4, mt, nh, l, acc);
    }
    store_C(ws, p, mt, nh, l, acc);
    arrive(pln);
    wait1(pln, 8u * (st + 1), &sDead);
    if (sDead) return;
    if (t < 512) {                               // reduce + pointwise
      const int cb = (k * 16 + u_pw) * 128 + row_pw;
      float v[32];
      #pragma unroll
      for (int sb = 0; sb < 8; ++sb)
        #pragma unroll
        for (int q = 0; q < 4; ++q)
          v[sb * 4 + q] = ld_f32(Cgrp + sb * 16384 + q * 512 + cb);
      float g0 = bq0, g1 = bq1, g2 = bq2, g3 = bq3;
      #pragma unroll
      for (int sb = 0; sb < 8; ++sb) {
        g0 += v[sb * 4]; g1 += v[sb * 4 + 1]; g2 += v[sb * 4 + 2]; g3 += v[sb * 4 + 3];
      }
      creg = sigm(g1) * creg + sigm(g0) * tanhfa(g2);
      float h = sigm(g3) * tanhfa(creg);
      short hi, lo; split2(h, hi, lo);
      hsplit[u_pw * 128 + row_pw] = ((unsigned)(unsigned short)hi << 16) | (unsigned short)lo;
    }
    __syncthreads();
    if (t < 128) {                               // pack h slice (units 4p..4p+3)
      int r = t;
      unsigned w0 = hsplit[r], w1 = hsplit[128 + r], w2 = hsplit[256 + r], w3 = hsplit[384 + r];
      unsigned long long hi64 = (unsigned long long)(w0 >> 16)
        | ((unsigned long long)(w1 >> 16) << 16)
        | ((unsigned long long)(w2 >> 16) << 32)
        | ((unsigned long long)(w3 >> 16) << 48);
      unsigned long long lo64 = (unsigned long long)(w0 & 0xFFFFu)
        | ((unsigned long long)(w1 & 0xFFFFu) << 16)
        | ((unsigned long long)(w2 & 0xFFFFu) << 32)
        | ((unsigned long long)(w3 & 0xFFFFu) << 48);
      int hk = p >> 3, mtt = r >> 4;
      int lane_ = (((p >> 1) & 3) << 4) | (r & 15);
      int off = ((hk * 8 + mtt) * 64 + lane_) * 8 + (p & 1) * 4;
      st_u64(hpH[wp] + off, hi64);
      st_u64(hpL[wp] + off, lo64);
    }
    arrive(my_hline);
  }

  // ================= switch to decoder =================
  load_gw(dWx, dWh, n, k, sBh, sBl);
  int kg = 0, cg = 0, row_sm = 0;
  if (k >= 4) {
    int f = n * 4 + (k - 4); kg = f >> 5; cg = f & 31;
    load_fcw(fcW, kg, cg, sFh, sFl);
  } else {
    row_sm = n * 4 + k;
  }
  if (t < 64) {                                  // zero y0
    int i64 = p * 64 + t;
    st_u64(ypH + i64 * 4, 0ull);
    st_u64(ypL + i64 * 4, 0ull);
  }
  creg = 0.0f;
  if (t < 512) {
    bq0 = db[0 * 1024 + p * 4 + u_pw];
    bq1 = db[1 * 1024 + p * 4 + u_pw];
    bq2 = db[2 * 1024 + p * 4 + u_pw];
    bq3 = db[3 * 1024 + p * 4 + u_pw];
  }
  float fcb_r = (t < 512) ? fcb[t] : 0.f;
  arrive(my_hline);                              // -> 64*DBASE

  // ================= decoder =================
  for (int st = 0; st < TS; ++st) {
    const int rp = st & 1, wp = rp ^ 1;
    f32x4 z = {0.f, 0.f, 0.f, 0.f};
    f32x4 acc[4] = {z, z, z, z};
    if (k >= 4) {
      wait4(hln, 64u * (DBASE + st), &sDead);
      if (sDead) return;
      gemm_h(hpH[rp], hpL[rp], sBh, sBl, k - 4, mt, nh, l, acc);
    } else {
      if (st == 0) { wait4(hln, 64u * DBASE, &sDead); if (sDead) return; }
      wait4(ylnB, 32u * st, &sDead);             // y(st-1) ready
      if (sDead) return;
      gemm_x_dec(ypH, ypL, sBh, sBl, k, mt, nh, l, acc);
    }
    store_C(ws, p, mt, nh, l, acc);
    arrive(pln);
    wait1(pln, 8u * (TS + st + 1), &sDead);
    if (sDead) return;
    if (t < 512) {
      const int cb = (k * 16 + u_pw) * 128 + row_pw;
      float v[32];
      #pragma unroll
      for (int sb = 0; sb < 8; ++sb)
        #pragma unroll
        for (int q = 0; q < 4; ++q)
          v[sb * 4 + q] = ld_f32(Cgrp + sb * 16384 + q * 512 + cb);
      float g0 = bq0, g1 = bq1, g2 = bq2, g3 = bq3;
      #pragma unroll
      for (int sb = 0; sb < 8; ++sb) {
        g0 += v[sb * 4]; g1 += v[sb * 4 + 1]; g2 += v[sb * 4 + 2]; g3 += v[sb * 4 + 3];
      }
      creg = sigm(g1) * creg + sigm(g0) * tanhfa(g2);
      float h = sigm(g3) * tanhfa(creg);
      short hi, lo; split2(h, hi, lo);
      hsplit[u_pw * 128 + row_pw] = ((unsigned)(unsigned short)hi << 16) | (unsigned short)lo;
    }
    __syncthreads();
    if (t < 128) {
      int r = t;
      unsigned w0 = hsplit[r], w1 = hsplit[128 + r], w2 = hsplit[256 + r], w3 = hsplit[384 + r];
      unsigned long long hi64 = (unsigned long long)(w0 >> 16)
        | ((unsigned long long)(w1 >> 16) << 16)
        | ((unsigned long long)(w2 >> 16) << 32)
        | ((unsigned long long)(w3 >> 16) << 48);
      unsigned long long lo64 = (unsigned long long)(w0 & 0xFFFFu)
        | ((unsigned long long)(w1 & 0xFFFFu) << 16)
        | ((unsigned long long)(w2 & 0xFFFFu) << 32)
        | ((unsigned long long)(w3 & 0xFFFFu) << 48);
      int hk = p >> 3, mtt = r >> 4;
      int lane_ = (((p >> 1) & 3) << 4) | (r & 15);
      int off = ((hk * 8 + mtt) * 64 + lane_) * 8 + (p & 1) * 4;
      st_u64(hpH[wp] + off, hi64);
      st_u64(hpL[wp] + off, lo64);
    }
    arrive(my_hline);

    if (k >= 4) {
      // ---- fc on h-blocks ----
      wait1(hln + kg * 64, 64u * (DBASE + st + 1), &sDead);
      if (sDead) return;
      {
        const bf16x8* FB = (const bf16x8*)sFh;
        const bf16x8* FL = (const bf16x8*)sFl;
        f32x4 a0 = z, a1 = z, a2 = z;
        #pragma unroll
        for (int kb = 0; kb < 4; ++kb) {
          int gkb = kg * 8 + nh * 4 + kb;
          bf16x8 ah = ld_frag(hpH[wp] + ((gkb * 8 + mt) * 64 + l) * 8);
          bf16x8 al = ld_frag(hpL[wp] + ((gkb * 8 + mt) * 64 + l) * 8);
          bf16x8 bh = FB[(nh * 4 + kb) * 64 + l];
          bf16x8 bl = FL[(nh * 4 + kb) * 64 + l];
          a0 = MFMA(ah, bh, a0, 0, 0, 0);
          a1 = MFMA(ah, bl, a1, 0, 0, 0);
          a2 = MFMA(al, bh, a2, 0, 0, 0);
        }
        f32x4 s = a0 + (a1 + a2);
        int slice = kg * 2 + nh;
        int col = cg * 16 + (l & 15), r0 = mt * 16 + ((l >> 4) << 2);
        #pragma unroll
        for (int j = 0; j < 4; ++j)
          st_f32(&fp[(size_t)(slice * 128 + r0 + j) * 512 + col], s[j]);
      }
      arrive(flnB + (n >> 3) * 64);
    } else {
      // ---- softmax + y-pack on x-blocks ----
      wait4(flnB, 32u * (st + 1), &sDead);
      if (sDead) return;
      float v = 0.f, e = 0.f, mx;
      if (t < 512) {
        v = fcb_r;
        #pragma unroll
        for (int s8 = 0; s8 < 8; ++s8)
          v += ld_f32(&fp[(size_t)(s8 * 128 + row_sm) * 512 + t]);
        mx = v;
        #pragma unroll
        for (int o = 32; o > 0; o >>= 1) mx = fmaxf(mx, __shfl_xor(mx, o));
        if (l == 0) red[w] = mx;
      }
      __syncthreads();
      if (t < 512) {
        mx = red[0];
        #pragma unroll
        for (int i = 1; i < 8; ++i) mx = fmaxf(mx, red[i]);
        e = __expf(v - mx);
        float ss = e;
        #pragma unroll
        for (int o = 32; o > 0; o >>= 1) ss += __shfl_xor(ss, o);
        if (l == 0) red[8 + w] = ss;
      }
      __syncthreads();
      if (t < 512) {
        float ss = (red[8] + red[9]) + (red[10] + red[11])
                 + (red[12] + red[13]) + (red[14] + red[15]);
        float y = e / ss;
        out[((size_t)st * 128 + row_sm) * 512 + t] = y;
        ybuf[t] = y;
      }
      __syncthreads();
      if (t < 64) {                              // pack y row row_sm
        int kb = t >> 2, seg = t & 3;
        int kcol = kb * 32 + seg * 8;
        int lane_ = (seg << 4) | (row_sm & 15), mtt = row_sm >> 4;
        int off = ((kb * 8 + mtt) * 64 + lane_) * 8;
        unsigned long long h64[2] = {0, 0}, l64[2] = {0, 0};
        #pragma unroll
        for (int j = 0; j < 8; ++j) {
          short hi, lo; split2(ybuf[kcol + j], hi, lo);
          h64[j >> 2] |= (unsigned long long)(unsigned short)hi << ((j & 3) * 16);
          l64[j >> 2] |= (unsigned long long)(unsigned short)lo << ((j & 3) * 16);
        }
        st_u64(ypH + off, h64[0]); st_u64(ypH + off + 4, h64[1]);
        st_u64(ypL + off, l64[0]); st_u64(ypL + off + 4, l64[1]);
      }
      arrive(ylnB + (n >> 3) * 64);
    }
  }
}

extern "C" void kernel_launch(void* const* d_in, const int* in_sizes, int n_in,
                              void* d_out, int out_size, void* d_ws, size_t ws_size,
                              hipStream_t stream) {
  const float* x   = (const float*)d_in[0];
  const float* h0  = (const float*)d_in[1];
  const float* c0  = (const float*)d_in[2];
  const float* eWx = (const float*)d_in[3];
  const float* eWh = (const float*)d_in[4];
  const float* eb  = (const float*)d_in[5];
  const float* dWx = (const float*)d_in[6];
  const float* dWh = (const float*)d_in[7];
  const float* db  = (const float*)d_in[8];
  const float* fcW = (const float*)d_in[9];
  const float* fcb = (const float*)d_in[10];
  float* out = (float*)d_out;

  if (ws_size < (size_t)WS_TOTAL) {
    hipMemsetAsync(d_out, 0xFF, (size_t)out_size * sizeof(float), stream);
    return;
  }
  hipMemsetAsync(d_ws, 0, 8192, stream);   // counter lines
  hipLaunchKernelGGL(lstm5, dim3(256), dim3(1024), 0, stream,
                     x, h0, c0, eWx, eWh, eb, dWx, dWh, db, fcW, fcb, out,
                     (char*)d_ws);
}

// Round 6
// 15767.476 us; speedup vs baseline: 1.5637x; 1.5637x over previous
//
#include <hip/hip_runtime.h>

// ---------------------------------------------------------------------------
// Persistent seq2seq LSTM, v6 = v4 structure + contention-free flag sync.
// 256 blocks x 1024 threads. Block p owns 16 gate cols (4 units x 4 gates),
// full K=1536; gates complete in-block; c in registers. K split across wave
// halves (kh), partial gate sums combined via two LDSgate planes.
// Memory: x in a 4-slot fragment-ordered ring (converted 2 steps ahead in
// encoder; y written by softmax in decoder, 2-slot alternation). h in 2
// alternating fragment-ordered planes. Cross-block payload written with
// agent-scope WT stores; A-operand reads are CACHED (L2-served, proven R4).
// Sync v6: per-block FLAG STORES (flag[p]=epoch, no atomics -> no hot-line
// serialization) + wave-parallel polls (64 lanes x 4 flags, one RTT/iter).
// One acquire fence per block per step (at the h-wait); all other waits
// fence-free. Decoder: fc on blocks 128..255, softmax+y on blocks 0..127.
// ---------------------------------------------------------------------------

#define TS 384

typedef __attribute__((ext_vector_type(8))) short bf16x8;
typedef __attribute__((ext_vector_type(4))) float f32x4;

// ws layout
#define WS_XR 4096u                      // x ring: 4 slots x (hi 128KB + lo 128KB)
#define XR_SLOT 262144u
#define WS_HP (WS_XR + 4u*XR_SLOT)       // h planes: 2 bufs x (hi 256KB + lo 256KB)
#define HP_BUF 524288u
#define WS_FPN (WS_HP + 2u*HP_BUF)       // fc partials 8*128*512*4 = 2MB
#define WS_TOTAL (WS_FPN + 2097152u)

__device__ __forceinline__ unsigned short bf16r(float v) {
  unsigned u = __float_as_uint(v);
  u += 0x7FFFu + ((u >> 16) & 1u);
  return (unsigned short)(u >> 16);
}
__device__ __forceinline__ float bf2f(unsigned short h) {
  return __uint_as_float(((unsigned)h) << 16);
}
__device__ __forceinline__ void split2(float v, short& hi, short& lo) {
  unsigned short h = bf16r(v);
  float r = v - bf2f(h);
  hi = (short)h; lo = (short)bf16r(r);
}
__device__ __forceinline__ float sigm(float v)  { return 1.0f / (1.0f + __expf(-v)); }
__device__ __forceinline__ float tanhfa(float v){ return 1.0f - 2.0f / (__expf(2.0f*v) + 1.0f); }

__device__ __forceinline__ void st_u64(void* p, unsigned long long v) {
  __hip_atomic_store((unsigned long long*)p, v, __ATOMIC_RELAXED, __HIP_MEMORY_SCOPE_AGENT);
}
__device__ __forceinline__ void st_f32(float* p, float v) {
  __hip_atomic_store(p, v, __ATOMIC_RELAXED, __HIP_MEMORY_SCOPE_AGENT);
}
__device__ __forceinline__ float ld_f32(const float* p) {
  return __hip_atomic_load(p, __ATOMIC_RELAXED, __HIP_MEMORY_SCOPE_AGENT);
}
union FRAG { unsigned long long q[2]; bf16x8 v; };
__device__ __forceinline__ bf16x8 ld_frag(const short* base) {
  FRAG u;
  u.q[0] = __hip_atomic_load((const unsigned long long*)base, __ATOMIC_RELAXED, __HIP_MEMORY_SCOPE_AGENT);
  u.q[1] = __hip_atomic_load((const unsigned long long*)(base + 4), __ATOMIC_RELAXED, __HIP_MEMORY_SCOPE_AGENT);
  return u.v;
}

// ---- flag sync --------------------------------------------------------------
// setflag: all payload drained (vmcnt0 + barrier), then ONE plain UC store.
__device__ __forceinline__ void setflag(unsigned* flag, unsigned val) {
  asm volatile("s_waitcnt vmcnt(0)" ::: "memory");
  __syncthreads();
  if (threadIdx.x == 0) {
    __hip_atomic_store(flag, val, __ATOMIC_RELAXED, __HIP_MEMORY_SCOPE_AGENT);
    asm volatile("s_waitcnt vmcnt(0)" ::: "memory");
  }
}
// waitflags: wave 0 polls nflags flags in parallel (4 per lane, u64 pairs).
__device__ __forceinline__ void waitflags(const unsigned* flags, int nflags,
                                          unsigned target, bool fence, int* sDead) {
  if (threadIdx.x < 64) {
    const int i = threadIdx.x;
    const bool act = (i * 4) < nflags;
    const unsigned long long* q = (const unsigned long long*)(flags + i * 4);
    unsigned spins = 0;
    for (;;) {
      bool ok = true;
      if (act) {
        unsigned long long q0 = __hip_atomic_load(q, __ATOMIC_RELAXED, __HIP_MEMORY_SCOPE_AGENT);
        unsigned long long q1 = __hip_atomic_load(q + 1, __ATOMIC_RELAXED, __HIP_MEMORY_SCOPE_AGENT);
        ok = ((unsigned)q0 >= target) && ((unsigned)(q0 >> 32) >= target)
          && ((unsigned)q1 >= target) && ((unsigned)(q1 >> 32) >= target);
      }
      if (__all(ok)) break;
      __builtin_amdgcn_s_sleep(1);
      if (++spins > (1u << 19)) { if (i == 0) *sDead = 1; break; }
    }
    if (fence) __builtin_amdgcn_fence(__ATOMIC_ACQUIRE, "agent");
  }
  __syncthreads();
}

// ---- weight loaders --------------------------------------------------------
__device__ void load_gate_weights(const float* __restrict__ Wx, const float* __restrict__ Wh,
                                  int p, short* sBh, short* sBl) {
  for (int idx = threadIdx.x; idx < 24576; idx += 1024) {
    int j = idx & 7, l = (idx >> 3) & 63, kb = idx >> 9;
    int k = kb * 32 + ((l >> 4) << 3) + j;
    int c = l & 15;
    int gcol = (c >> 2) * 1024 + p * 4 + (c & 3);
    float wv = (k < 512) ? Wx[(size_t)k * 4096 + gcol]
                         : Wh[(size_t)(k - 512) * 4096 + gcol];
    short hi, lo; split2(wv, hi, lo);
    sBh[idx] = hi; sBl[idx] = lo;
  }
}
__device__ void load_fc_weights(const float* __restrict__ fcW, int kg, int cg,
                                short* sFh, short* sFl) {
  for (int idx = threadIdx.x; idx < 4096; idx += 1024) {
    int j = idx & 7, l = (idx >> 3) & 63, kb = idx >> 9;
    int unit = kg * 256 + kb * 32 + ((l >> 4) << 3) + j;
    int col = cg * 16 + (l & 15);
    short hi, lo; split2(fcW[(size_t)unit * 512 + col], hi, lo);
    sFh[idx] = hi; sFl[idx] = lo;
  }
}

// ---- gate GEMM range (A-local kb indexing, B-global kb), split-bf16 --------
__device__ __forceinline__ void gg(const short* AHs, const short* ALs,
    const short* BHs, const short* BLs, int mt, int l,
    int kbA0, int kbB0, int nkb, f32x4* acc)
{
  const bf16x8* AH = (const bf16x8*)AHs;
  const bf16x8* AL = (const bf16x8*)ALs;
  const bf16x8* BH = (const bf16x8*)BHs;
  const bf16x8* BL = (const bf16x8*)BLs;
  #pragma unroll 2
  for (int i = 0; i < nkb; i += 2) {
    int ka = kbA0 + i, kb = kbB0 + i;
    bf16x8 ah0 = AH[(ka * 8 + mt) * 64 + l];
    bf16x8 al0 = AL[(ka * 8 + mt) * 64 + l];
    bf16x8 bh0 = BH[kb * 64 + l];
    bf16x8 bl0 = BL[kb * 64 + l];
    bf16x8 ah1 = AH[((ka + 1) * 8 + mt) * 64 + l];
    bf16x8 al1 = AL[((ka + 1) * 8 + mt) * 64 + l];
    bf16x8 bh1 = BH[(kb + 1) * 64 + l];
    bf16x8 bl1 = BL[(kb + 1) * 64 + l];
    acc[0] = __builtin_amdgcn_mfma_f32_16x16x32_bf16(ah0, bh0, acc[0], 0, 0, 0);
    acc[1] = __builtin_amdgcn_mfma_f32_16x16x32_bf16(ah0, bl0, acc[1], 0, 0, 0);
    acc[2] = __builtin_amdgcn_mfma_f32_16x16x32_bf16(al0, bh0, acc[2], 0, 0, 0);
    acc[3] = __builtin_amdgcn_mfma_f32_16x16x32_bf16(ah1, bh1, acc[3], 0, 0, 0);
    acc[4] = __builtin_amdgcn_mfma_f32_16x16x32_bf16(ah1, bl1, acc[4], 0, 0, 0);
    acc[5] = __builtin_amdgcn_mfma_f32_16x16x32_bf16(al1, bh1, acc[5], 0, 0, 0);
  }
}
__device__ __forceinline__ void gg_finish(f32x4* acc, int kh, int mt, int l,
                                          float* LDSgate) {
  f32x4 s = (acc[0] + acc[3]) + ((acc[1] + acc[4]) + (acc[2] + acc[5]));
  const int col = l & 15, r0 = mt * 16 + ((l >> 4) << 2);
  float* plane = LDSgate + kh * 2176;
  #pragma unroll
  for (int j = 0; j < 4; ++j) plane[(r0 + j) * 17 + col] = s[j];
}

// ---- x conversion into fragment-ordered x-ring slot ------------------------
__device__ __forceinline__ void conv_x(const float* __restrict__ xsrc,
                                       short* dstH, short* dstL, int p, int t) {
  if (t < 32) {
    int g = p * 32 + t;                       // 0..8191
    int l = g & 63, mt = (g >> 6) & 7, kb = g >> 9;
    int row = mt * 16 + (l & 15), k = kb * 32 + ((l >> 4) << 3);
    const float* xs = xsrc + (size_t)row * 512 + k;
    unsigned long long h64[2] = {0, 0}, l64[2] = {0, 0};
    #pragma unroll
    for (int j = 0; j < 8; ++j) {
      short hi, lo; split2(xs[j], hi, lo);
      h64[j >> 2] |= (unsigned long long)(unsigned short)hi << ((j & 3) * 16);
      l64[j >> 2] |= (unsigned long long)(unsigned short)lo << ((j & 3) * 16);
    }
    int off = g * 8;
    st_u64(dstH + off, h64[0]); st_u64(dstH + off + 4, h64[1]);
    st_u64(dstL + off, l64[0]); st_u64(dstL + off + 4, l64[1]);
  }
}

__global__ void __launch_bounds__(1024, 1)
lstm6(const float* __restrict__ x, const float* __restrict__ h0p,
      const float* __restrict__ c0p, const float* __restrict__ eWx,
      const float* __restrict__ eWh, const float* __restrict__ eb,
      const float* __restrict__ dWx, const float* __restrict__ dWh,
      const float* __restrict__ db, const float* __restrict__ fcW,
      const float* __restrict__ fcb, float* __restrict__ out,
      char* __restrict__ ws)
{
  __shared__ __align__(16) short sBh[24576], sBl[24576];   // 96 KB
  __shared__ __align__(16) short sFh[4096], sFl[4096];     // 16 KB
  __shared__ float LDSgate[2 * 2176];                      // 17.4 KB
  __shared__ unsigned hsplit[512];
  __shared__ float ybuf[512];
  __shared__ float red[16];
  __shared__ int sDead;

  const int p = blockIdx.x, t = threadIdx.x;
  const int w = t >> 6, l = t & 63;
  const int mt = w & 7, kh = w >> 3;
  if (t == 0) sDead = 0;

  unsigned* hflag = (unsigned*)ws;                 // 256 flags
  unsigned* yflag = (unsigned*)(ws + 1024);        // 128 flags (p<128)
  unsigned* fflag = (unsigned*)(ws + 2048);        // 128 flags (p-128)

  short* xrH[4]; short* xrL[4];
  #pragma unroll
  for (int s4 = 0; s4 < 4; ++s4) {
    xrH[s4] = (short*)(ws + WS_XR + s4 * XR_SLOT);
    xrL[s4] = (short*)(ws + WS_XR + s4 * XR_SLOT + 131072u);
  }
  short* hpH[2]; short* hpL[2];
  #pragma unroll
  for (int b2 = 0; b2 < 2; ++b2) {
    hpH[b2] = (short*)(ws + WS_HP + b2 * HP_BUF);
    hpL[b2] = (short*)(ws + WS_HP + b2 * HP_BUF + 262144u);
  }
  float* fp = (float*)(ws + WS_FPN);

  const int row_pw = t & 127, u_pw = (t >> 7) & 3;

  // ================= init =================
  load_gate_weights(eWx, eWh, p, sBh, sBl);
  conv_x(x, xrH[0], xrL[0], p, t);                       // x(0)
  conv_x(x + 65536, xrH[1], xrL[1], p, t);               // x(1)
  if (t < 64) {                                          // h0 -> hp[0]
    int hg = p * 64 + t;
    int ll = hg & 63, mtt = (hg >> 6) & 7, hk = hg >> 9;
    int row = mtt * 16 + (ll & 15), k = hk * 32 + ((ll >> 4) << 3);
    const float* hs = h0p + (size_t)row * 1024 + k;
    unsigned long long h64[2] = {0, 0}, l64[2] = {0, 0};
    #pragma unroll
    for (int j = 0; j < 8; ++j) {
      short hi, lo; split2(hs[j], hi, lo);
      h64[j >> 2] |= (unsigned long long)(unsigned short)hi << ((j & 3) * 16);
      l64[j >> 2] |= (unsigned long long)(unsigned short)lo << ((j & 3) * 16);
    }
    int off = hg * 8;
    st_u64(hpH[0] + off, h64[0]); st_u64(hpH[0] + off + 4, h64[1]);
    st_u64(hpL[0] + off, l64[0]); st_u64(hpL[0] + off + 4, l64[1]);
  }
  float creg = 0.f, bq0 = 0.f, bq1 = 0.f, bq2 = 0.f, bq3 = 0.f;
  if (t < 512) {
    creg = c0p[(size_t)row_pw * 1024 + p * 4 + u_pw];
    bq0 = eb[0 * 1024 + p * 4 + u_pw];
    bq1 = eb[1 * 1024 + p * 4 + u_pw];
    bq2 = eb[2 * 1024 + p * 4 + u_pw];
    bq3 = eb[3 * 1024 + p * 4 + u_pw];
  }
  setflag(&hflag[p], 1u);                                // epoch 1
  waitflags(hflag, 256, 1u, true, &sDead);               // init barrier (fix v4 race)
  if (sDead) return;

  // ================= encoder =================
  // epochs: enc step st waits (st+1), stores (st+2)
  for (int st = 0; st < TS; ++st) {
    int rb = st & 1, wb = rb ^ 1, xs = st & 3;
    f32x4 z = {0.f, 0.f, 0.f, 0.f};
    f32x4 acc[6] = {z, z, z, z, z, z};
    // x-part BEFORE the wait (x(st) readiness implied by passed epochs)
    gg(xrH[xs], xrL[xs], sBh, sBl, mt, l, kh * 8, kh * 8, 8, acc);
    waitflags(hflag, 256, (unsigned)(st + 1), true, &sDead);   // the one fence/step
    if (sDead) return;
    gg(hpH[rb], hpL[rb], sBh, sBl, mt, l, kh * 16, 16 + kh * 16, 16, acc);
    gg_finish(acc, kh, mt, l, LDSgate);
    __syncthreads();
    if (t < 512) {
      float g0 = LDSgate[row_pw * 17 + 0  + u_pw] + LDSgate[2176 + row_pw * 17 + 0  + u_pw] + bq0;
      float g1 = LDSgate[row_pw * 17 + 4  + u_pw] + LDSgate[2176 + row_pw * 17 + 4  + u_pw] + bq1;
      float g2 = LDSgate[row_pw * 17 + 8  + u_pw] + LDSgate[2176 + row_pw * 17 + 8  + u_pw] + bq2;
      float g3 = LDSgate[row_pw * 17 + 12 + u_pw] + LDSgate[2176 + row_pw * 17 + 12 + u_pw] + bq3;
      creg = sigm(g1) * creg + sigm(g0) * tanhfa(g2);
      float h = sigm(g3) * tanhfa(creg);
      short hi, lo; split2(h, hi, lo);
      hsplit[u_pw * 128 + row_pw] = ((unsigned)(unsigned short)hi << 16) | (unsigned short)lo;
    }
    if (st + 2 < TS)
      conv_x(x + (size_t)(st + 2) * 65536, xrH[(st + 2) & 3], xrL[(st + 2) & 3], p, t);
    __syncthreads();
    if (t < 128) {                                       // pack h slice (4 units)
      int r = t;
      unsigned w0 = hsplit[r], w1 = hsplit[128 + r], w2 = hsplit[256 + r], w3 = hsplit[384 + r];
      unsigned long long hi64 = (unsigned long long)(w0 >> 16)
        | ((unsigned long long)(w1 >> 16) << 16)
        | ((unsigned long long)(w2 >> 16) << 32)
        | ((unsigned long long)(w3 >> 16) << 48);
      unsigned long long lo64 = (unsigned long long)(w0 & 0xFFFFu)
        | ((unsigned long long)(w1 & 0xFFFFu) << 16)
        | ((unsigned long long)(w2 & 0xFFFFu) << 32)
        | ((unsigned long long)(w3 & 0xFFFFu) << 48);
      int hk = p >> 3, mtt = r >> 4;
      int lane_ = (((p >> 1) & 3) << 4) | (r & 15);
      int off = ((hk * 8 + mtt) * 64 + lane_) * 8 + (p & 1) * 4;
      st_u64(hpH[wb] + off, hi64);
      st_u64(hpL[wb] + off, lo64);
    }
    setflag(&hflag[p], (unsigned)(st + 2));
  }

  // ================= switch to decoder =================
  // after encoder hflag = TS+1; switch stores TS+2
  load_gate_weights(dWx, dWh, p, sBh, sBl);
  if (p >= 128) load_fc_weights(fcW, (p - 128) >> 5, (p - 128) & 31, sFh, sFl);
  if (t < 32) {                                          // zero y0 (slot 0)
    int off = (p * 32 + t) * 8;
    st_u64(xrH[0] + off, 0ull); st_u64(xrH[0] + off + 4, 0ull);
    st_u64(xrL[0] + off, 0ull); st_u64(xrL[0] + off + 4, 0ull);
  }
  creg = 0.0f;
  if (t < 512) {
    bq0 = db[0 * 1024 + p * 4 + u_pw];
    bq1 = db[1 * 1024 + p * 4 + u_pw];
    bq2 = db[2 * 1024 + p * 4 + u_pw];
    bq3 = db[3 * 1024 + p * 4 + u_pw];
  }
  float fcb_r = (t < 512) ? fcb[t] : 0.f;
  setflag(&hflag[p], (unsigned)(TS + 2));

  // ================= decoder =================
  // epochs: dec step st waits h(TS+2+st), stores h(TS+3+st);
  //         yflag: waits st, stores st+1; fflag: waits/stores st+1.
  const unsigned DB = (unsigned)(TS + 2);
  for (int st = 0; st < TS; ++st) {
    int rb = st & 1, wb = rb ^ 1;
    int ys = st & 1, yw = ys ^ 1;
    f32x4 z = {0.f, 0.f, 0.f, 0.f};
    f32x4 acc[6] = {z, z, z, z, z, z};
    waitflags(hflag, 256, DB + (unsigned)st, true, &sDead);    // the one fence/step
    if (sDead) return;
    gg(hpH[rb], hpL[rb], sBh, sBl, mt, l, kh * 16, 16 + kh * 16, 16, acc);
    waitflags(yflag, 128, (unsigned)st, false, &sDead);        // y(st-1)
    if (sDead) return;
    gg(xrH[ys], xrL[ys], sBh, sBl, mt, l, kh * 8, kh * 8, 8, acc);
    gg_finish(acc, kh, mt, l, LDSgate);
    __syncthreads();
    if (t < 512) {
      float g0 = LDSgate[row_pw * 17 + 0  + u_pw] + LDSgate[2176 + row_pw * 17 + 0  + u_pw] + bq0;
      float g1 = LDSgate[row_pw * 17 + 4  + u_pw] + LDSgate[2176 + row_pw * 17 + 4  + u_pw] + bq1;
      float g2 = LDSgate[row_pw * 17 + 8  + u_pw] + LDSgate[2176 + row_pw * 17 + 8  + u_pw] + bq2;
      float g3 = LDSgate[row_pw * 17 + 12 + u_pw] + LDSgate[2176 + row_pw * 17 + 12 + u_pw] + bq3;
      creg = sigm(g1) * creg + sigm(g0) * tanhfa(g2);
      float h = sigm(g3) * tanhfa(creg);
      short hi, lo; split2(h, hi, lo);
      hsplit[u_pw * 128 + row_pw] = ((unsigned)(unsigned short)hi << 16) | (unsigned short)lo;
    }
    __syncthreads();
    if (t < 128) {
      int r = t;
      unsigned w0 = hsplit[r], w1 = hsplit[128 + r], w2 = hsplit[256 + r], w3 = hsplit[384 + r];
      unsigned long long hi64 = (unsigned long long)(w0 >> 16)
        | ((unsigned long long)(w1 >> 16) << 16)
        | ((unsigned long long)(w2 >> 16) << 32)
        | ((unsigned long long)(w3 >> 16) << 48);
      unsigned long long lo64 = (unsigned long long)(w0 & 0xFFFFu)
        | ((unsigned long long)(w1 & 0xFFFFu) << 16)
        | ((unsigned long long)(w2 & 0xFFFFu) << 32)
        | ((unsigned long long)(w3 & 0xFFFFu) << 48);
      int hk = p >> 3, mtt = r >> 4;
      int lane_ = (((p >> 1) & 3) << 4) | (r & 15);
      int off = ((hk * 8 + mtt) * 64 + lane_) * 8 + (p & 1) * 4;
      st_u64(hpH[wb] + off, hi64);
      st_u64(hpL[wb] + off, lo64);
    }
    setflag(&hflag[p], DB + (unsigned)(st + 1));          // h(st) ready

    if (p >= 128) {
      // ---- fc GEMM on blocks 128..255 (UC hp reads -> no fence needed) ----
      const int f = p - 128, kg = f >> 5, cg = f & 31;
      waitflags(hflag + kg * 64, 64, DB + (unsigned)(st + 1), false, &sDead);
      if (sDead) return;
      {
        const bf16x8* FB = (const bf16x8*)sFh;
        const bf16x8* FL = (const bf16x8*)sFl;
        f32x4 a0 = z, a1 = z, a2 = z;
        #pragma unroll
        for (int kb = 0; kb < 4; ++kb) {
          int gkb = kg * 8 + kh * 4 + kb;
          bf16x8 ah = ld_frag(hpH[wb] + ((gkb * 8 + mt) * 64 + l) * 8);
          bf16x8 al = ld_frag(hpL[wb] + ((gkb * 8 + mt) * 64 + l) * 8);
          bf16x8 bh = FB[(kh * 4 + kb) * 64 + l];
          bf16x8 bl = FL[(kh * 4 + kb) * 64 + l];
          a0 = __builtin_amdgcn_mfma_f32_16x16x32_bf16(ah, bh, a0, 0, 0, 0);
          a1 = __builtin_amdgcn_mfma_f32_16x16x32_bf16(ah, bl, a1, 0, 0, 0);
          a2 = __builtin_amdgcn_mfma_f32_16x16x32_bf16(al, bh, a2, 0, 0, 0);
        }
        f32x4 s = a0 + (a1 + a2);
        int slice = kg * 2 + kh;
        int col = cg * 16 + (l & 15), r0 = mt * 16 + ((l >> 4) << 2);
        #pragma unroll
        for (int j = 0; j < 4; ++j)
          st_f32(&fp[(size_t)(slice * 128 + r0 + j) * 512 + col], s[j]);
      }
      setflag(&fflag[f], (unsigned)(st + 1));
    } else {
      // ---- softmax + y-pack on blocks 0..127 (UC fp reads -> no fence) ----
      waitflags(fflag, 128, (unsigned)(st + 1), false, &sDead);
      if (sDead) return;
      float v = 0.f, e = 0.f, mx;
      if (t < 512) {
        v = fcb_r;
        #pragma unroll
        for (int s8 = 0; s8 < 8; ++s8)
          v += ld_f32(&fp[(size_t)(s8 * 128 + p) * 512 + t]);
        mx = v;
        #pragma unroll
        for (int o = 32; o > 0; o >>= 1) mx = fmaxf(mx, __shfl_xor(mx, o));
        if (l == 0) red[w] = mx;
      }
      __syncthreads();
      if (t < 512) {
        mx = red[0];
        #pragma unroll
        for (int i = 1; i < 8; ++i) mx = fmaxf(mx, red[i]);
        e = __expf(v - mx);
        float ss = e;
        #pragma unroll
        for (int o = 32; o > 0; o >>= 1) ss += __shfl_xor(ss, o);
        if (l == 0) red[8 + w] = ss;
      }
      __syncthreads();
      if (t < 512) {
        float ss = (red[8] + red[9]) + (red[10] + red[11])
                 + (red[12] + red[13]) + (red[14] + red[15]);
        float y = e / ss;
        out[((size_t)st * 128 + p) * 512 + t] = y;
        ybuf[t] = y;
      }
      __syncthreads();
      if (t < 64) {                                      // pack y row p
        int kb = t >> 2, seg = t & 3;
        int k = kb * 32 + seg * 8;
        int lane_ = (seg << 4) | (p & 15), mtt = p >> 4;
        int off = ((kb * 8 + mtt) * 64 + lane_) * 8;
        unsigned long long h64[2] = {0, 0}, l64[2] = {0, 0};
        #pragma unroll
        for (int j = 0; j < 8; ++j) {
          short hi, lo; split2(ybuf[k + j], hi, lo);
          h64[j >> 2] |= (unsigned long long)(unsigned short)hi << ((j & 3) * 16);
          l64[j >> 2] |= (unsigned long long)(unsigned short)lo << ((j & 3) * 16);
        }
        st_u64(xrH[yw] + off, h64[0]); st_u64(xrH[yw] + off + 4, h64[1]);
        st_u64(xrL[yw] + off, l64[0]); st_u64(xrL[yw] + off + 4, l64[1]);
      }
      setflag(&yflag[p], (unsigned)(st + 1));
    }
  }
}

extern "C" void kernel_launch(void* const* d_in, const int* in_sizes, int n_in,
                              void* d_out, int out_size, void* d_ws, size_t ws_size,
                              hipStream_t stream) {
  const float* x   = (const float*)d_in[0];
  const float* h0  = (const float*)d_in[1];
  const float* c0  = (const float*)d_in[2];
  const float* eWx = (const float*)d_in[3];
  const float* eWh = (const float*)d_in[4];
  const float* eb  = (const float*)d_in[5];
  const float* dWx = (const float*)d_in[6];
  const float* dWh = (const float*)d_in[7];
  const float* db  = (const float*)d_in[8];
  const float* fcW = (const float*)d_in[9];
  const float* fcb = (const float*)d_in[10];
  float* out = (float*)d_out;

  if (ws_size < (size_t)WS_TOTAL) {
    hipMemsetAsync(d_out, 0xFF, (size_t)out_size * sizeof(float), stream);
    return;
  }
  hipMemsetAsync(d_ws, 0, 4096, stream);   // flag arrays
  hipLaunchKernelGGL(lstm6, dim3(256), dim3(1024), 0, stream,
                     x, h0, c0, eWx, eWh, eb, dWx, dWh, db, fcW, fcb, out,
                     (char*)d_ws);
}